// Round 2
// baseline (239.628 us; speedup 1.0000x reference)
//
#include <hip/hip_runtime.h>

typedef _Float16 f16_t;
typedef f16_t f16x8 __attribute__((ext_vector_type(8)));
typedef float f32x4 __attribute__((ext_vector_type(4)));

#define DEVI __device__ __forceinline__

constexpr int NB    = 64;
constexpr int NTOK  = 197;
constexpr int NH    = 12;
constexpr int DIM   = 768;
constexpr int M_TOK = NB * NTOK;   // 12608
constexpr int NPAD  = 224;         // 14*16 padded token count
constexpr int VT_LD = 232;         // vt / P row stride (f16 elems), 464B = 29*16B
constexpr float SCALE = 0.125f;    // 64^-0.5

DEVI ushort f2h_bits(float f) { _Float16 h = (_Float16)f; return __builtin_bit_cast(ushort, h); }

DEVI void gload16(const void* g, void* l) {
    __builtin_amdgcn_global_load_lds((const __attribute__((address_space(1))) void*)g,
                                     (__attribute__((address_space(3))) void*)l, 16, 0, 0);
}

// ---------------- fp32 -> fp16 convert ----------------
__global__ __launch_bounds__(256) void k_cvt(const float* __restrict__ in, ushort* __restrict__ out, int n4) {
    int i = blockIdx.x * 256 + threadIdx.x;
    if (i >= n4) return;
    float4 v = reinterpret_cast<const float4*>(in)[i];
    ushort4 o;
    o.x = f2h_bits(v.x); o.y = f2h_bits(v.y); o.z = f2h_bits(v.z); o.w = f2h_bits(v.w);
    reinterpret_cast<ushort4*>(out)[i] = o;
}

// ---------------- rel-pos bias gather (mask baked into pad cols) ----------------
__global__ __launch_bounds__(256) void k_bias(const float* __restrict__ rel_table,
                                              const int* __restrict__ rel_index,
                                              float* __restrict__ bias) {
    int idx = blockIdx.x * 256 + threadIdx.x;
    if (idx >= NH * NTOK * NPAD) return;
    int j = idx % NPAD;
    int rem = idx / NPAD;
    int i = rem % NTOK;
    int h = rem / NTOK;
    float v = -1e30f;
    if (j < NTOK) v = rel_table[rel_index[i * NTOK + j] * NH + h];
    bias[idx] = v;
}

// ---------------- 128x128 BT GEMM (m97 structure), f16 in, f32 acc ----------------
// EPI 0: qkv epilogue (q:(+qb)*scale | k | v:+vb), f16 out [M][2304]
// EPI 1: proj epilogue (+bproj), f32 out [M][768]
template<int EPI>
__global__ __launch_bounds__(256) void k_gemm(const ushort* __restrict__ A, const ushort* __restrict__ BT,
                                              int M, int N, int K,
                                              const float* __restrict__ b_q, const float* __restrict__ b_v,
                                              const float* __restrict__ b_p,
                                              ushort* __restrict__ out_h, float* __restrict__ out_f) {
    __shared__ __align__(16) ushort As[128 * 32];
    __shared__ __align__(16) ushort Bs[128 * 32];
    const int tid = threadIdx.x;
    const int wid = tid >> 6, lane = tid & 63;
    const int wm = wid >> 1, wn = wid & 1;
    const int m0 = blockIdx.y * 128, n0 = blockIdx.x * 128;
    const int l4 = lane >> 2, ls = lane & 3;   // staging: row-in-chunk, 16B segment
    const int fr = lane & 15, fg = lane >> 4;  // fragment: row/col, k-group
    f32x4 acc[4][4] = {};

    for (int k0 = 0; k0 < K; k0 += 32) {
#pragma unroll
        for (int p = 0; p < 2; ++p) {
            const int chunk = 2 * wid + p;                 // 0..7 -> 16 rows each
            int row = m0 + chunk * 16 + l4;
            row = row < M ? row : M - 1;                   // clamp tail rows (stores masked)
            gload16(A + (size_t)row * K + k0 + ls * 8, As + chunk * 512);
            const int rowb = n0 + chunk * 16 + l4;         // N multiple of 128
            gload16(BT + (size_t)rowb * K + k0 + ls * 8, Bs + chunk * 512);
        }
        __syncthreads();
        f16x8 af[4], bfv[4];
#pragma unroll
        for (int i = 0; i < 4; ++i)
            af[i] = *reinterpret_cast<const f16x8*>(As + (wm * 64 + i * 16 + fr) * 32 + fg * 8);
#pragma unroll
        for (int i = 0; i < 4; ++i)
            bfv[i] = *reinterpret_cast<const f16x8*>(Bs + (wn * 64 + i * 16 + fr) * 32 + fg * 8);
#pragma unroll
        for (int mi = 0; mi < 4; ++mi)
#pragma unroll
            for (int ni = 0; ni < 4; ++ni)
                acc[mi][ni] = __builtin_amdgcn_mfma_f32_16x16x32_f16(af[mi], bfv[ni], acc[mi][ni], 0, 0, 0);
        __syncthreads();
    }

#pragma unroll
    for (int ni = 0; ni < 4; ++ni) {
        const int col = n0 + wn * 64 + ni * 16 + fr;
        float addv = 0.f, mul = 1.f;
        if (EPI == 0) {
            if (col < 768)       { addv = b_q[col]; mul = SCALE; }
            else if (col < 1536) { addv = 0.f; }
            else                 { addv = b_v[col - 1536]; }
        } else {
            addv = b_p[col];
        }
#pragma unroll
        for (int mi = 0; mi < 4; ++mi) {
#pragma unroll
            for (int r = 0; r < 4; ++r) {
                const int row = m0 + wm * 64 + mi * 16 + fg * 4 + r;
                if (row < M) {
                    float v = (acc[mi][ni][r] + addv) * mul;
                    if (EPI == 0) out_h[(size_t)row * N + col] = f2h_bits(v);
                    else          out_f[(size_t)row * N + col] = v;
                }
            }
        }
    }
}

// ---------------- V transpose: qkv v-slice [197][64] -> vt [b,h][64][VT_LD] (zero-padded) ---------
__global__ __launch_bounds__(256) void k_vt(const ushort* __restrict__ qkv, ushort* __restrict__ vt) {
    constexpr int LD = 72;  // padded row stride (144B) to break bank alignment
    __shared__ __align__(16) ushort tile[NPAD * LD];
    const int bh = blockIdx.x;
    const int b = bh / NH, h = bh % NH;
    const size_t base = (size_t)(b * NTOK) * 2304 + 1536 + h * 64;
    // FIX: 8 segments x 8 ushorts (16B) per 64-elem row (was 4 x stride-16 -> gaps)
    for (int t = threadIdx.x; t < NPAD * 8; t += 256) {
        const int row = t >> 3, seg = t & 7;
        uint4 val = make_uint4(0u, 0u, 0u, 0u);
        if (row < NTOK) val = *reinterpret_cast<const uint4*>(qkv + base + (size_t)row * 2304 + seg * 8);
        *reinterpret_cast<uint4*>(tile + row * LD + seg * 8) = val;
    }
    __syncthreads();
    ushort* outp = vt + (size_t)bh * (64 * VT_LD);
    for (int t = threadIdx.x; t < 64 * 29; t += 256) {
        const int d = t / 29, c = t % 29;
        uint w0 = 0, w1 = 0, w2 = 0, w3 = 0;
        if (c < 28) {
            const int nb = c * 8;
            w0 = (uint)tile[(nb + 0) * LD + d] | ((uint)tile[(nb + 1) * LD + d] << 16);
            w1 = (uint)tile[(nb + 2) * LD + d] | ((uint)tile[(nb + 3) * LD + d] << 16);
            w2 = (uint)tile[(nb + 4) * LD + d] | ((uint)tile[(nb + 5) * LD + d] << 16);
            w3 = (uint)tile[(nb + 6) * LD + d] | ((uint)tile[(nb + 7) * LD + d] << 16);
        }
        *reinterpret_cast<uint4*>(outp + (size_t)d * VT_LD + c * 8) = make_uint4(w0, w1, w2, w3);
    }
}

// ---------------- fused attention: block = (64-row q-tile, h, b), 4 waves ----------------
__global__ __launch_bounds__(256) void k_attn(const ushort* __restrict__ qkv, const ushort* __restrict__ vt,
                                              const float* __restrict__ bias, ushort* __restrict__ out) {
    constexpr int KLD = 72;      // K rows padded (144B) -> 2-way max bank conflict
    constexpr int PLD = VT_LD;   // P/VT rows (464B)
    __shared__ __align__(16) ushort kp[NPAD * KLD];   // 32256B; K tile, later reused as P[64][PLD]
    __shared__ __align__(16) ushort vts[64 * PLD];    // 29696B
    const int tid = threadIdx.x, wid = tid >> 6, lane = tid & 63;
    const int fr = lane & 15, fg = lane >> 4;
    const int qt = blockIdx.x, h = blockIdx.y, b = blockIdx.z;
    const int q0 = qt * 64;
    const size_t qb = (size_t)(b * NTOK) * 2304;

    // K -> LDS (rows >=197 zeroed)
    // FIX: 8 segments x 8 ushorts (16B) per 64-elem row (was 4 x stride-16 -> gaps)
    for (int t = tid; t < NPAD * 8; t += 256) {
        const int row = t >> 3, seg = t & 7;
        uint4 val = make_uint4(0u, 0u, 0u, 0u);
        if (row < NTOK) val = *reinterpret_cast<const uint4*>(qkv + qb + (size_t)row * 2304 + 768 + h * 64 + seg * 8);
        *reinterpret_cast<uint4*>(kp + row * KLD + seg * 8) = val;
    }
    // VT -> LDS (flat copy, layouts identical)
    const ushort* vtg = vt + (size_t)(b * NH + h) * (64 * VT_LD);
    for (int t = tid; t < 64 * VT_LD / 8; t += 256)
        *reinterpret_cast<uint4*>(vts + t * 8) = *reinterpret_cast<const uint4*>(vtg + t * 8);
    // Q fragments straight from global (A-frag rows = fr)
    f16x8 qf[2];
    {
        int row = q0 + wid * 16 + fr;
        row = row < NTOK ? row : NTOK - 1;
        const ushort* qp = qkv + qb + (size_t)row * 2304 + h * 64 + fg * 8;
        qf[0] = *reinterpret_cast<const f16x8*>(qp);
        qf[1] = *reinterpret_cast<const f16x8*>(qp + 32);
    }
    __syncthreads();

    // S = Q K^T  (wave's 16-row strip x 224 cols)
    f32x4 s[14] = {};
#pragma unroll
    for (int j = 0; j < 14; ++j) {
#pragma unroll
        for (int kh = 0; kh < 2; ++kh) {
            f16x8 kf = *reinterpret_cast<const f16x8*>(kp + (j * 16 + fr) * KLD + kh * 32 + fg * 8);
            s[j] = __builtin_amdgcn_mfma_f32_16x16x32_f16(qf[kh], kf, s[j], 0, 0, 0);
        }
    }
    __syncthreads();   // all waves done reading K; kp becomes P

    // bias + masked softmax (row's 16 cols live in one 16-lane shfl group)
    float rs[4];
#pragma unroll
    for (int r = 0; r < 4; ++r) {
        const int qrow_l = wid * 16 + fg * 4 + r;
        int qrow = q0 + qrow_l;
        qrow = qrow < NTOK ? qrow : NTOK - 1;
        const float* bp = bias + (size_t)(h * NTOK + qrow) * NPAD + fr;
        float mx = -1e30f;
#pragma unroll
        for (int j = 0; j < 14; ++j) {
            float v = s[j][r] + bp[j * 16];  // pad cols carry -1e30 -> masked
            s[j][r] = v;
            mx = fmaxf(mx, v);
        }
        mx = fmaxf(mx, __shfl_xor(mx, 1));
        mx = fmaxf(mx, __shfl_xor(mx, 2));
        mx = fmaxf(mx, __shfl_xor(mx, 4));
        mx = fmaxf(mx, __shfl_xor(mx, 8));
        float sum = 0.f;
        ushort* prow = kp + qrow_l * PLD;
#pragma unroll
        for (int j = 0; j < 14; ++j) {
            float p = __expf(s[j][r] - mx);
            sum += p;
            prow[j * 16 + fr] = f2h_bits(p);
        }
        sum += __shfl_xor(sum, 1);
        sum += __shfl_xor(sum, 2);
        sum += __shfl_xor(sum, 4);
        sum += __shfl_xor(sum, 8);
        rs[r] = sum;
    }
    __syncthreads();

    // O = P V   (K-dim padded to 224; pad P cols are exp(-1e30)=0)
    f32x4 o[4] = {};
#pragma unroll
    for (int kc = 0; kc < 7; ++kc) {
        f16x8 af = *reinterpret_cast<const f16x8*>(kp + (wid * 16 + fr) * PLD + kc * 32 + fg * 8);
#pragma unroll
        for (int dt = 0; dt < 4; ++dt) {
            f16x8 bv = *reinterpret_cast<const f16x8*>(vts + (dt * 16 + fr) * PLD + kc * 32 + fg * 8);
            o[dt] = __builtin_amdgcn_mfma_f32_16x16x32_f16(af, bv, o[dt], 0, 0, 0);
        }
    }
#pragma unroll
    for (int dt = 0; dt < 4; ++dt) {
#pragma unroll
        for (int r = 0; r < 4; ++r) {
            const int qrow = q0 + wid * 16 + fg * 4 + r;
            if (qrow < NTOK) {
                const float val = o[dt][r] / rs[r];
                out[(size_t)(b * NTOK + qrow) * DIM + h * 64 + dt * 16 + fr] = f2h_bits(val);
            }
        }
    }
}

extern "C" void kernel_launch(void* const* d_in, const int* in_sizes, int n_in,
                              void* d_out, int out_size, void* d_ws, size_t ws_size,
                              hipStream_t stream) {
    const float* x         = (const float*)d_in[0];
    const float* Wqkv      = (const float*)d_in[1];
    const float* q_bias    = (const float*)d_in[2];
    const float* v_bias    = (const float*)d_in[3];
    const float* rel_table = (const float*)d_in[4];
    const float* Wproj     = (const float*)d_in[5];
    const float* bproj     = (const float*)d_in[6];
    const int*   rel_index = (const int*)d_in[7];
    float* out = (float*)d_out;

    char* p = (char*)d_ws;
    auto alloc = [&](size_t bytes) { char* r = p; p += (bytes + 255) & ~(size_t)255; return r; };
    ushort* xb     = (ushort*)alloc((size_t)M_TOK * DIM * 2);
    ushort* wqkvb  = (ushort*)alloc((size_t)2304 * 768 * 2);
    ushort* wprojb = (ushort*)alloc((size_t)768 * 768 * 2);
    ushort* qkvb   = (ushort*)alloc((size_t)M_TOK * 2304 * 2);
    ushort* vtb    = (ushort*)alloc((size_t)NB * NH * 64 * VT_LD * 2);
    float*  biasb  = (float*)alloc((size_t)NH * NTOK * NPAD * 4);
    ushort* aob    = (ushort*)alloc((size_t)M_TOK * DIM * 2);

    int n4 = M_TOK * DIM / 4;
    k_cvt<<<(n4 + 255) / 256, 256, 0, stream>>>(x, xb, n4);
    n4 = 2304 * 768 / 4;
    k_cvt<<<(n4 + 255) / 256, 256, 0, stream>>>(Wqkv, wqkvb, n4);
    n4 = 768 * 768 / 4;
    k_cvt<<<(n4 + 255) / 256, 256, 0, stream>>>(Wproj, wprojb, n4);
    int nbias = NH * NTOK * NPAD;
    k_bias<<<(nbias + 255) / 256, 256, 0, stream>>>(rel_table, rel_index, biasb);

    k_gemm<0><<<dim3(2304 / 128, (M_TOK + 127) / 128), 256, 0, stream>>>(
        xb, wqkvb, M_TOK, 2304, 768, q_bias, v_bias, nullptr, qkvb, nullptr);
    k_vt<<<NB * NH, 256, 0, stream>>>(qkvb, vtb);
    k_attn<<<dim3(4, NH, NB), 256, 0, stream>>>(qkvb, vtb, biasb, aob);
    k_gemm<1><<<dim3(768 / 128, (M_TOK + 127) / 128), 256, 0, stream>>>(
        aob, wprojb, M_TOK, 768, 768, nullptr, nullptr, bproj, nullptr, out);
}

// Round 3
// 222.770 us; speedup vs baseline: 1.0757x; 1.0757x over previous
//
#include <hip/hip_runtime.h>

typedef _Float16 f16_t;
typedef f16_t f16x8 __attribute__((ext_vector_type(8)));
typedef float f32x4 __attribute__((ext_vector_type(4)));

#define DEVI __device__ __forceinline__

constexpr int NB    = 64;
constexpr int NTOK  = 197;
constexpr int NH    = 12;
constexpr int DIM   = 768;
constexpr int M_TOK = NB * NTOK;   // 12608
constexpr int NPAD  = 224;         // 14*16 padded token count
constexpr int VT_LD = 232;         // vt / P row stride (f16 elems), 464B = 29*16B
constexpr float SCALE = 0.125f;    // 64^-0.5

DEVI ushort f2h_bits(float f) { _Float16 h = (_Float16)f; return __builtin_bit_cast(ushort, h); }

DEVI void gload16(const void* g, void* l) {
    __builtin_amdgcn_global_load_lds((const __attribute__((address_space(1))) void*)g,
                                     (__attribute__((address_space(3))) void*)l, 16, 0, 0);
}

// ---------------- fp32 -> fp16 convert ----------------
__global__ __launch_bounds__(256) void k_cvt(const float* __restrict__ in, ushort* __restrict__ out, int n4) {
    int i = blockIdx.x * 256 + threadIdx.x;
    if (i >= n4) return;
    float4 v = reinterpret_cast<const float4*>(in)[i];
    ushort4 o;
    o.x = f2h_bits(v.x); o.y = f2h_bits(v.y); o.z = f2h_bits(v.z); o.w = f2h_bits(v.w);
    reinterpret_cast<ushort4*>(out)[i] = o;
}

// ---------------- rel-pos bias gather (mask baked into pad cols) ----------------
__global__ __launch_bounds__(256) void k_bias(const float* __restrict__ rel_table,
                                              const int* __restrict__ rel_index,
                                              float* __restrict__ bias) {
    int idx = blockIdx.x * 256 + threadIdx.x;
    if (idx >= NH * NTOK * NPAD) return;
    int j = idx % NPAD;
    int rem = idx / NPAD;
    int i = rem % NTOK;
    int h = rem / NTOK;
    float v = -1e30f;
    if (j < NTOK) v = rel_table[rel_index[i * NTOK + j] * NH + h];
    bias[idx] = v;
}

// ---------------- 256x256 BT GEMM, BK=64, 8 waves, dbuf LDS + st_16x32 swizzle ----------------
// 2-phase prefetch: STAGE(t+1) issued before compute(t); one __syncthreads per K-tile
// (its implicit vmcnt(0)+lgkmcnt(0) drain completes the prefetch). LDS: A[2][256*64] | B[2][256*64] f16.
// Swizzle (T2): logical byte b within a 32KB tile lives at b ^ (((b>>9)&1)<<5).
//   write side: linear gload_lds dest granule g takes SOURCE granule g ^ (((g>>5)&1)<<1)  (involution)
//   read  side: ds_read at byte ^ ((row&4)<<3)
template<int EPI>
__global__ __launch_bounds__(512, 2) void k_gemm8(const ushort* __restrict__ A, const ushort* __restrict__ BT,
                                                  int M, int N, int K,
                                                  const float* __restrict__ b_q, const float* __restrict__ b_v,
                                                  const float* __restrict__ b_p,
                                                  ushort* __restrict__ out_h, float* __restrict__ out_f) {
    extern __shared__ ushort lds[];  // 65536 ushorts = 128 KiB
    const int tid = threadIdx.x, wid = tid >> 6, lane = tid & 63;
    const int wm = wid >> 2, wn = wid & 3;          // 2 x 4 wave grid, wave tile 128x64
    const int fr = lane & 15, fg = lane >> 4;
    const int m0 = blockIdx.y * 256, n0 = blockIdx.x * 256;

    // staging source coords (swizzle-inverse), fixed per thread across K-tiles
    int rowAg[4], rowBg[4], colo[4];
#pragma unroll
    for (int i = 0; i < 4; ++i) {
        const int gl = i * 512 + tid;                    // linear LDS granule (16B) within tile
        const int gs = gl ^ (((gl >> 5) & 1) << 1);      // inverse-swizzled logical granule
        const int r = gs >> 3;
        colo[i] = (gs & 7) * 8;                          // ushort offset within row
        const int ra = m0 + r;
        rowAg[i] = ra < M ? ra : M - 1;                  // clamp (stores masked)
        rowBg[i] = n0 + r;                               // N multiple of 256
    }
    const int ldsoff = wid * 512;                        // wave chunk (64 granules) in ushorts

    f32x4 acc[8][4] = {};
    const int nt = K / 64;

    // prologue: stage tile 0 -> buf 0
#pragma unroll
    for (int i = 0; i < 4; ++i)
        gload16(A + (size_t)rowAg[i] * K + colo[i], lds + i * 4096 + ldsoff);
#pragma unroll
    for (int i = 0; i < 4; ++i)
        gload16(BT + (size_t)rowBg[i] * K + colo[i], lds + 32768 + i * 4096 + ldsoff);
    __syncthreads();

    for (int t = 0; t < nt; ++t) {
        const int cur = t & 1;
        if (t + 1 < nt) {                                // prefetch next tile into other buffer
            const int nb = cur ^ 1;
            const int k0 = (t + 1) * 64;
#pragma unroll
            for (int i = 0; i < 4; ++i)
                gload16(A + (size_t)rowAg[i] * K + k0 + colo[i], lds + nb * 16384 + i * 4096 + ldsoff);
#pragma unroll
            for (int i = 0; i < 4; ++i)
                gload16(BT + (size_t)rowBg[i] * K + k0 + colo[i], lds + 32768 + nb * 16384 + i * 4096 + ldsoff);
        }
        const char* As = (const char*)(lds + cur * 16384);
        const char* Bs = (const char*)(lds + 32768 + cur * 16384);
#pragma unroll
        for (int q = 0; q < 4; ++q) {                    // quadrant: 16 MFMA each
            const int mh = q >> 1, nh = q & 1;
            f16x8 av[4][2], bv[2][2];
#pragma unroll
            for (int mi = 0; mi < 4; ++mi) {
                const int r = wm * 128 + (mh * 4 + mi) * 16 + fr;
                const int base = r * 128 + fg * 16;
                const int sw = (r & 4) << 3;
#pragma unroll
                for (int ks = 0; ks < 2; ++ks)
                    av[mi][ks] = *(const f16x8*)(As + ((base + ks * 64) ^ sw));
            }
#pragma unroll
            for (int ni = 0; ni < 2; ++ni) {
                const int c = wn * 64 + (nh * 2 + ni) * 16 + fr;
                const int base = c * 128 + fg * 16;
                const int sw = (c & 4) << 3;
#pragma unroll
                for (int ks = 0; ks < 2; ++ks)
                    bv[ni][ks] = *(const f16x8*)(Bs + ((base + ks * 64) ^ sw));
            }
#pragma unroll
            for (int ks = 0; ks < 2; ++ks)
#pragma unroll
                for (int mi = 0; mi < 4; ++mi)
#pragma unroll
                    for (int ni = 0; ni < 2; ++ni)
                        acc[mh * 4 + mi][nh * 2 + ni] = __builtin_amdgcn_mfma_f32_16x16x32_f16(
                            av[mi][ks], bv[ni][ks], acc[mh * 4 + mi][nh * 2 + ni], 0, 0, 0);
        }
        __syncthreads();
    }

    // epilogue
#pragma unroll
    for (int nf = 0; nf < 4; ++nf) {
        const int col = n0 + wn * 64 + nf * 16 + fr;
        float addv = 0.f, mul = 1.f;
        if (EPI == 0) {
            if (col < 768)       { addv = b_q[col]; mul = SCALE; }
            else if (col < 1536) { addv = 0.f; }
            else                 { addv = b_v[col - 1536]; }
        } else {
            addv = b_p[col];
        }
#pragma unroll
        for (int mf = 0; mf < 8; ++mf) {
#pragma unroll
            for (int rr = 0; rr < 4; ++rr) {
                const int row = m0 + wm * 128 + mf * 16 + fg * 4 + rr;
                if (row < M) {
                    float v = (acc[mf][nf][rr] + addv) * mul;
                    if (EPI == 0) out_h[(size_t)row * N + col] = f2h_bits(v);
                    else          out_f[(size_t)row * N + col] = v;
                }
            }
        }
    }
}

// ---------------- V transpose: qkv v-slice [197][64] -> vt [b,h][64][VT_LD] (zero-padded) ---------
__global__ __launch_bounds__(256) void k_vt(const ushort* __restrict__ qkv, ushort* __restrict__ vt) {
    constexpr int LD = 72;  // padded row stride (144B) to break bank alignment
    __shared__ __align__(16) ushort tile[NPAD * LD];
    const int bh = blockIdx.x;
    const int b = bh / NH, h = bh % NH;
    const size_t base = (size_t)(b * NTOK) * 2304 + 1536 + h * 64;
    for (int t = threadIdx.x; t < NPAD * 8; t += 256) {
        const int row = t >> 3, seg = t & 7;
        uint4 val = make_uint4(0u, 0u, 0u, 0u);
        if (row < NTOK) val = *reinterpret_cast<const uint4*>(qkv + base + (size_t)row * 2304 + seg * 8);
        *reinterpret_cast<uint4*>(tile + row * LD + seg * 8) = val;
    }
    __syncthreads();
    ushort* outp = vt + (size_t)bh * (64 * VT_LD);
    for (int t = threadIdx.x; t < 64 * 29; t += 256) {
        const int d = t / 29, c = t % 29;
        uint w0 = 0, w1 = 0, w2 = 0, w3 = 0;
        if (c < 28) {
            const int nb = c * 8;
            w0 = (uint)tile[(nb + 0) * LD + d] | ((uint)tile[(nb + 1) * LD + d] << 16);
            w1 = (uint)tile[(nb + 2) * LD + d] | ((uint)tile[(nb + 3) * LD + d] << 16);
            w2 = (uint)tile[(nb + 4) * LD + d] | ((uint)tile[(nb + 5) * LD + d] << 16);
            w3 = (uint)tile[(nb + 6) * LD + d] | ((uint)tile[(nb + 7) * LD + d] << 16);
        }
        *reinterpret_cast<uint4*>(outp + (size_t)d * VT_LD + c * 8) = make_uint4(w0, w1, w2, w3);
    }
}

// ---------------- fused attention: block = (64-row q-tile, h, b), 4 waves ----------------
__global__ __launch_bounds__(256) void k_attn(const ushort* __restrict__ qkv, const ushort* __restrict__ vt,
                                              const float* __restrict__ bias, ushort* __restrict__ out) {
    constexpr int KLD = 72;      // K rows padded (144B) -> 2-way max bank conflict
    constexpr int PLD = VT_LD;   // P/VT rows (464B)
    __shared__ __align__(16) ushort kp[NPAD * KLD];   // 32256B; K tile, later reused as P[64][PLD]
    __shared__ __align__(16) ushort vts[64 * PLD];    // 29696B
    const int tid = threadIdx.x, wid = tid >> 6, lane = tid & 63;
    const int fr = lane & 15, fg = lane >> 4;
    const int qt = blockIdx.x, h = blockIdx.y, b = blockIdx.z;
    const int q0 = qt * 64;
    const size_t qb = (size_t)(b * NTOK) * 2304;

    for (int t = tid; t < NPAD * 8; t += 256) {
        const int row = t >> 3, seg = t & 7;
        uint4 val = make_uint4(0u, 0u, 0u, 0u);
        if (row < NTOK) val = *reinterpret_cast<const uint4*>(qkv + qb + (size_t)row * 2304 + 768 + h * 64 + seg * 8);
        *reinterpret_cast<uint4*>(kp + row * KLD + seg * 8) = val;
    }
    const ushort* vtg = vt + (size_t)(b * NH + h) * (64 * VT_LD);
    for (int t = tid; t < 64 * VT_LD / 8; t += 256)
        *reinterpret_cast<uint4*>(vts + t * 8) = *reinterpret_cast<const uint4*>(vtg + t * 8);
    f16x8 qf[2];
    {
        int row = q0 + wid * 16 + fr;
        row = row < NTOK ? row : NTOK - 1;
        const ushort* qp = qkv + qb + (size_t)row * 2304 + h * 64 + fg * 8;
        qf[0] = *reinterpret_cast<const f16x8*>(qp);
        qf[1] = *reinterpret_cast<const f16x8*>(qp + 32);
    }
    __syncthreads();

    f32x4 s[14] = {};
#pragma unroll
    for (int j = 0; j < 14; ++j) {
#pragma unroll
        for (int kh = 0; kh < 2; ++kh) {
            f16x8 kf = *reinterpret_cast<const f16x8*>(kp + (j * 16 + fr) * KLD + kh * 32 + fg * 8);
            s[j] = __builtin_amdgcn_mfma_f32_16x16x32_f16(qf[kh], kf, s[j], 0, 0, 0);
        }
    }
    __syncthreads();

    float rs[4];
#pragma unroll
    for (int r = 0; r < 4; ++r) {
        const int qrow_l = wid * 16 + fg * 4 + r;
        int qrow = q0 + qrow_l;
        qrow = qrow < NTOK ? qrow : NTOK - 1;
        const float* bp = bias + (size_t)(h * NTOK + qrow) * NPAD + fr;
        float mx = -1e30f;
#pragma unroll
        for (int j = 0; j < 14; ++j) {
            float v = s[j][r] + bp[j * 16];
            s[j][r] = v;
            mx = fmaxf(mx, v);
        }
        mx = fmaxf(mx, __shfl_xor(mx, 1));
        mx = fmaxf(mx, __shfl_xor(mx, 2));
        mx = fmaxf(mx, __shfl_xor(mx, 4));
        mx = fmaxf(mx, __shfl_xor(mx, 8));
        float sum = 0.f;
        ushort* prow = kp + qrow_l * PLD;
#pragma unroll
        for (int j = 0; j < 14; ++j) {
            float p = __expf(s[j][r] - mx);
            sum += p;
            prow[j * 16 + fr] = f2h_bits(p);
        }
        sum += __shfl_xor(sum, 1);
        sum += __shfl_xor(sum, 2);
        sum += __shfl_xor(sum, 4);
        sum += __shfl_xor(sum, 8);
        rs[r] = sum;
    }
    __syncthreads();

    f32x4 o[4] = {};
#pragma unroll
    for (int kc = 0; kc < 7; ++kc) {
        f16x8 af = *reinterpret_cast<const f16x8*>(kp + (wid * 16 + fr) * PLD + kc * 32 + fg * 8);
#pragma unroll
        for (int dt = 0; dt < 4; ++dt) {
            f16x8 bv = *reinterpret_cast<const f16x8*>(vts + (dt * 16 + fr) * PLD + kc * 32 + fg * 8);
            o[dt] = __builtin_amdgcn_mfma_f32_16x16x32_f16(af, bv, o[dt], 0, 0, 0);
        }
    }
#pragma unroll
    for (int dt = 0; dt < 4; ++dt) {
#pragma unroll
        for (int r = 0; r < 4; ++r) {
            const int qrow = q0 + wid * 16 + fg * 4 + r;
            if (qrow < NTOK) {
                const float val = o[dt][r] / rs[r];
                out[(size_t)(b * NTOK + qrow) * DIM + h * 64 + dt * 16 + fr] = f2h_bits(val);
            }
        }
    }
}

extern "C" void kernel_launch(void* const* d_in, const int* in_sizes, int n_in,
                              void* d_out, int out_size, void* d_ws, size_t ws_size,
                              hipStream_t stream) {
    const float* x         = (const float*)d_in[0];
    const float* Wqkv      = (const float*)d_in[1];
    const float* q_bias    = (const float*)d_in[2];
    const float* v_bias    = (const float*)d_in[3];
    const float* rel_table = (const float*)d_in[4];
    const float* Wproj     = (const float*)d_in[5];
    const float* bproj     = (const float*)d_in[6];
    const int*   rel_index = (const int*)d_in[7];
    float* out = (float*)d_out;

    char* p = (char*)d_ws;
    auto alloc = [&](size_t bytes) { char* r = p; p += (bytes + 255) & ~(size_t)255; return r; };
    ushort* xb     = (ushort*)alloc((size_t)M_TOK * DIM * 2);
    ushort* wqkvb  = (ushort*)alloc((size_t)2304 * 768 * 2);
    ushort* wprojb = (ushort*)alloc((size_t)768 * 768 * 2);
    ushort* qkvb   = (ushort*)alloc((size_t)M_TOK * 2304 * 2);
    ushort* vtb    = (ushort*)alloc((size_t)NB * NH * 64 * VT_LD * 2);
    float*  biasb  = (float*)alloc((size_t)NH * NTOK * NPAD * 4);
    ushort* aob    = (ushort*)alloc((size_t)M_TOK * DIM * 2);

    // allow 128 KiB dynamic LDS (host-side attribute, capture-safe, deterministic)
    (void)hipFuncSetAttribute((const void*)k_gemm8<0>, hipFuncAttributeMaxDynamicSharedMemorySize, 131072);
    (void)hipFuncSetAttribute((const void*)k_gemm8<1>, hipFuncAttributeMaxDynamicSharedMemorySize, 131072);

    int n4 = M_TOK * DIM / 4;
    k_cvt<<<(n4 + 255) / 256, 256, 0, stream>>>(x, xb, n4);
    n4 = 2304 * 768 / 4;
    k_cvt<<<(n4 + 255) / 256, 256, 0, stream>>>(Wqkv, wqkvb, n4);
    n4 = 768 * 768 / 4;
    k_cvt<<<(n4 + 255) / 256, 256, 0, stream>>>(Wproj, wprojb, n4);
    int nbias = NH * NTOK * NPAD;
    k_bias<<<(nbias + 255) / 256, 256, 0, stream>>>(rel_table, rel_index, biasb);

    k_gemm8<0><<<dim3(2304 / 256, (M_TOK + 255) / 256), 512, 131072, stream>>>(
        xb, wqkvb, M_TOK, 2304, 768, q_bias, v_bias, nullptr, qkvb, nullptr);
    k_vt<<<NB * NH, 256, 0, stream>>>(qkvb, vtb);
    k_attn<<<dim3(4, NH, NB), 256, 0, stream>>>(qkvb, vtb, biasb, aob);
    k_gemm8<1><<<dim3(768 / 256, (M_TOK + 255) / 256), 512, 131072, stream>>>(
        aob, wprojb, M_TOK, 768, 768, nullptr, nullptr, bproj, nullptr, out);
}